// Round 2
// baseline (17390.942 us; speedup 1.0000x reference)
//
#include <hip/hip_runtime.h>
#include <stdint.h>
#include <math.h>

// ---------------------------------------------------------------------------
// Model_14104672600612 — fp32 graph-attention pipeline on MI355X (gfx950)
// Round-2 theory: inputs/outputs are float32 (per reference source); round-1
// NaN came from reading fp32 buffers as bf16. Full fp32 vector-ALU compute
// (no fp32 MFMA on CDNA4). Comparison threshold is 2% rel (bf16 floor), and
// fp32 compute keeps the top-k node ranking stable vs the np reference.
// ---------------------------------------------------------------------------

#define BS 256
#define SEQ 201
#define DS 1024
#define D1 128
#define D2 64
#define NN 67
#define NP 53
#define ROWS1 (BS * SEQ)   // 51456
#define ROWS2 (BS * NN)    // 17152

#define SELU_LAM 1.0507009873554805f
#define SELU_ALP 1.6732632423543772f

__device__ __forceinline__ float selu_f(float x) {
    return (x > 0.0f) ? SELU_LAM * x : SELU_LAM * (SELU_ALP * expm1f(x));
}

// ---------------------------------------------------------------------------
// k_pre: WllT[c][k] = Wll[k][c] (128x1024), WapT[c][d] = Wap[d][c] (64x128),
// r1/r2 = 1/sqrt(var+eps).
// ---------------------------------------------------------------------------
__global__ __launch_bounds__(256) void k_pre(
    const float* __restrict__ Wll, const float* __restrict__ Wap,
    const float* __restrict__ v1, const float* __restrict__ v2,
    float* __restrict__ WllT, float* __restrict__ WapT,
    float* __restrict__ r1, float* __restrict__ r2)
{
    int t = blockIdx.x * 256 + threadIdx.x;
    if (t < 131072) {
        int c = t >> 10, k = t & 1023;
        WllT[t] = Wll[k * D1 + c];
    } else if (t < 139264) {
        int i = t - 131072; int c = i >> 7, d = i & 127;
        WapT[i] = Wap[d * D2 + c];
    } else if (t < 139392) {
        int d = t - 139264;
        r1[d] = 1.0f / sqrtf(v1[d] + 1e-5f);
    } else if (t < 139456) {
        int c = t - 139392;
        r2[c] = 1.0f / sqrtf(v2[c] + 1e-5f);
    }
}

// ---------------------------------------------------------------------------
// k_gemm1: y(51456x128) = feat(51456x1024) @ Wll. fp32 tiled 64x128,
// micro-tile 4x8 per thread, A rows i = ty+16r (lane-stride-1 -> 2-way LDS
// bank alias only), B^T staged from WllT.
// ---------------------------------------------------------------------------
__global__ __launch_bounds__(256) void k_gemm1(
    const float* __restrict__ A, const float* __restrict__ Bt,
    float* __restrict__ y)
{
    __shared__ __align__(16) float As[64 * 36];   // stride 36: 16B-aligned rows
    __shared__ __align__(16) float Bs[128 * 36];
    int tid = threadIdx.x;
    int row0 = blockIdx.x * 64;
    int ty = tid >> 4, tx = tid & 15;
    float acc[4][8];
#pragma unroll
    for (int r = 0; r < 4; ++r)
#pragma unroll
        for (int m = 0; m < 8; ++m) acc[r][m] = 0.0f;

    int si = tid >> 2, sk = (tid & 3) * 8;        // A staging: row si, cols sk..+7
    int bc = tid >> 1, bh = (tid & 1) * 16;       // B staging: row bc, cols bh..+15
    const float* gA = A + (size_t)(row0 + si) * DS + sk;
    const float* gB = Bt + (size_t)bc * DS + bh;

    for (int k0 = 0; k0 < DS; k0 += 32) {
        float4 a0 = *(const float4*)(gA + k0);
        float4 a1 = *(const float4*)(gA + k0 + 4);
        float4 b0 = *(const float4*)(gB + k0);
        float4 b1 = *(const float4*)(gB + k0 + 4);
        float4 b2 = *(const float4*)(gB + k0 + 8);
        float4 b3 = *(const float4*)(gB + k0 + 12);
        __syncthreads();
        *(float4*)(As + si * 36 + sk)      = a0;
        *(float4*)(As + si * 36 + sk + 4)  = a1;
        *(float4*)(Bs + bc * 36 + bh)      = b0;
        *(float4*)(Bs + bc * 36 + bh + 4)  = b1;
        *(float4*)(Bs + bc * 36 + bh + 8)  = b2;
        *(float4*)(Bs + bc * 36 + bh + 12) = b3;
        __syncthreads();
#pragma unroll
        for (int k4 = 0; k4 < 8; ++k4) {
            float4 av[4], bv[8];
#pragma unroll
            for (int r = 0; r < 4; ++r)
                av[r] = *(const float4*)(As + (ty + 16 * r) * 36 + k4 * 4);
#pragma unroll
            for (int m = 0; m < 8; ++m)
                bv[m] = *(const float4*)(Bs + (tx + 16 * m) * 36 + k4 * 4);
#pragma unroll
            for (int r = 0; r < 4; ++r)
#pragma unroll
                for (int m = 0; m < 8; ++m) {
                    acc[r][m] += av[r].x * bv[m].x;
                    acc[r][m] += av[r].y * bv[m].y;
                    acc[r][m] += av[r].z * bv[m].z;
                    acc[r][m] += av[r].w * bv[m].w;
                }
        }
    }
#pragma unroll
    for (int r = 0; r < 4; ++r)
#pragma unroll
        for (int m = 0; m < 8; ++m)
            y[(size_t)(row0 + ty + 16 * r) * D1 + tx + 16 * m] = acc[r][m];
}

// ---------------------------------------------------------------------------
// k_pool: +b_ll, maxpool3 over seq, BN1, SELU -> X (17152x128)
// ---------------------------------------------------------------------------
__global__ __launch_bounds__(256) void k_pool(
    const float* __restrict__ y, const float* __restrict__ bll,
    const float* __restrict__ g1, const float* __restrict__ b1,
    const float* __restrict__ m1, const float* __restrict__ r1,
    float* __restrict__ X)
{
    int t = blockIdx.x * 256 + threadIdx.x;    // 17152*128 total
    int d = t & 127, rem = t >> 7;
    int n = rem % NN, b = rem / NN;
    size_t base = ((size_t)(b * SEQ + 3 * n)) * D1 + d;
    float bl = bll[d];
    float v0 = y[base] + bl;
    float v1v = y[base + D1] + bl;
    float v2v = y[base + 2 * D1] + bl;
    float v = fmaxf(fmaxf(v0, v1v), v2v);
    v = (v - m1[d]) * r1[d] * g1[d] + b1[d];
    X[(size_t)rem * D1 + d] = selu_f(v);
}

// ---------------------------------------------------------------------------
// k_attn: one block (256 thr) per batch b. For c in [0,64):
//   Y_c[i][d] = X[i][d]*Wap[d][c]  (LDS), E_c = Y_c @ X^T (5x5 regs/thread,
//   16x16 thread grid over 80x80), e[i][j] += tanh(E_c + bap[c])*attw[c].
// Then softmax over j and xa = att @ X.
// ---------------------------------------------------------------------------
__global__ __launch_bounds__(256) void k_attn(
    const float* __restrict__ X, const float* __restrict__ WapT,
    const float* __restrict__ bap, const float* __restrict__ attw,
    float* __restrict__ XA)
{
    __shared__ __align__(16) float Xs[80 * 132];
    __shared__ __align__(16) float Ys[80 * 132];   // reused as Att (stride 84)
    int tid = threadIdx.x;
    int b = blockIdx.x;
    const float* Xb = X + (size_t)b * NN * D1;

    // stage Xs: rows 0..66 from global, rows 67..79 zero
#pragma unroll
    for (int q = 0; q < 40; ++q) {
        int e = q * 256 + tid;
        int r = e >> 7, d = e & 127;
        Xs[r * 132 + d] = (r < NN) ? Xb[(size_t)r * D1 + d] : 0.0f;
    }
    int ti = tid >> 4, tj = tid & 15;
    float eacc[5][5];
#pragma unroll
    for (int a = 0; a < 5; ++a)
#pragma unroll
        for (int m = 0; m < 5; ++m) eacc[a][m] = 0.0f;
    __syncthreads();

    for (int c = 0; c < D2; ++c) {
        // Y-prep (vectorized): Ys = Xs * W[:,c]
#pragma unroll
        for (int q = 0; q < 10; ++q) {
            int e4 = q * 256 + tid;
            int r = e4 >> 5, d4 = (e4 & 31) * 4;
            float4 xv = *(const float4*)(Xs + r * 132 + d4);
            float4 wv = *(const float4*)(WapT + c * D1 + d4);
            float4 yv;
            yv.x = xv.x * wv.x; yv.y = xv.y * wv.y;
            yv.z = xv.z * wv.z; yv.w = xv.w * wv.w;
            *(float4*)(Ys + r * 132 + d4) = yv;
        }
        __syncthreads();
        float bc = bap[c], ac = attw[c];
        float E[5][5];
#pragma unroll
        for (int a = 0; a < 5; ++a)
#pragma unroll
            for (int m = 0; m < 5; ++m) E[a][m] = 0.0f;
#pragma unroll
        for (int k4 = 0; k4 < 32; ++k4) {
            float4 ya[5], xv[5];
#pragma unroll
            for (int a = 0; a < 5; ++a)
                ya[a] = *(const float4*)(Ys + (ti + 16 * a) * 132 + k4 * 4);
#pragma unroll
            for (int m = 0; m < 5; ++m)
                xv[m] = *(const float4*)(Xs + (tj + 16 * m) * 132 + k4 * 4);
#pragma unroll
            for (int a = 0; a < 5; ++a)
#pragma unroll
                for (int m = 0; m < 5; ++m) {
                    E[a][m] += ya[a].x * xv[m].x;
                    E[a][m] += ya[a].y * xv[m].y;
                    E[a][m] += ya[a].z * xv[m].z;
                    E[a][m] += ya[a].w * xv[m].w;
                }
        }
#pragma unroll
        for (int a = 0; a < 5; ++a)
#pragma unroll
            for (int m = 0; m < 5; ++m)
                eacc[a][m] += tanhf(E[a][m] + bc) * ac;
        __syncthreads();   // E-compute done before Ys overwritten next c
    }

    // softmax over j per row i; store att into Ys with stride 84 (2-way banks)
    float* Att = Ys;
#pragma unroll
    for (int a = 0; a < 5; ++a) {
        int i = ti + 16 * a;
        float mx = -1e30f;
#pragma unroll
        for (int m = 0; m < 5; ++m) {
            int j = tj + 16 * m;
            if (j < NN) mx = fmaxf(mx, eacc[a][m]);
        }
        mx = fmaxf(mx, __shfl_xor(mx, 1));
        mx = fmaxf(mx, __shfl_xor(mx, 2));
        mx = fmaxf(mx, __shfl_xor(mx, 4));
        mx = fmaxf(mx, __shfl_xor(mx, 8));
        float p[5]; float sum = 0.0f;
#pragma unroll
        for (int m = 0; m < 5; ++m) {
            int j = tj + 16 * m;
            p[m] = (j < NN) ? expf(eacc[a][m] - mx) : 0.0f;
            sum += p[m];
        }
        sum += __shfl_xor(sum, 1);
        sum += __shfl_xor(sum, 2);
        sum += __shfl_xor(sum, 4);
        sum += __shfl_xor(sum, 8);
        if (i < NN) {
#pragma unroll
            for (int m = 0; m < 5; ++m) {
                int j = tj + 16 * m;
                if (j < NN) Att[i * 84 + j] = p[m] / sum;
            }
        }
    }
    __syncthreads();

    // xa[i][d] = sum_j att[i][j] * X[j][d]; thread: d = tj*8..+7, i = ti+16a
    int d0 = tj * 8;
    float o[5][8];
#pragma unroll
    for (int a = 0; a < 5; ++a)
#pragma unroll
        for (int dd = 0; dd < 8; ++dd) o[a][dd] = 0.0f;
    for (int j = 0; j < NN; ++j) {
        float4 x0 = *(const float4*)(Xs + j * 132 + d0);
        float4 x1 = *(const float4*)(Xs + j * 132 + d0 + 4);
        float av[5];
#pragma unroll
        for (int a = 0; a < 5; ++a) av[a] = Att[(ti + 16 * a) * 84 + j];
#pragma unroll
        for (int a = 0; a < 5; ++a) {
            o[a][0] += av[a] * x0.x; o[a][1] += av[a] * x0.y;
            o[a][2] += av[a] * x0.z; o[a][3] += av[a] * x0.w;
            o[a][4] += av[a] * x1.x; o[a][5] += av[a] * x1.y;
            o[a][6] += av[a] * x1.z; o[a][7] += av[a] * x1.w;
        }
    }
#pragma unroll
    for (int a = 0; a < 5; ++a) {
        int i = ti + 16 * a;
        if (i < NN) {
            float* dst = XA + (size_t)(b * NN + i) * D1 + d0;
            float4 s0, s1;
            s0.x = o[a][0]; s0.y = o[a][1]; s0.z = o[a][2]; s0.w = o[a][3];
            s1.x = o[a][4]; s1.y = o[a][5]; s1.z = o[a][6]; s1.w = o[a][7];
            *(float4*)(dst) = s0;
            *(float4*)(dst + 4) = s1;
        }
    }
}

// ---------------------------------------------------------------------------
// k_gemm2: h = selu(bn2( xa@Wpa + bpa + x@Wpn + bpn )). 64 rows/block,
// A rows (xa|x) and Wcat staged in LDS (136 KB).
// ---------------------------------------------------------------------------
__global__ __launch_bounds__(256) void k_gemm2(
    const float* __restrict__ XAg, const float* __restrict__ Xg,
    const float* __restrict__ Wpa, const float* __restrict__ Wpn,
    const float* __restrict__ bpa, const float* __restrict__ bpn,
    const float* __restrict__ g2, const float* __restrict__ b2,
    const float* __restrict__ m2, const float* __restrict__ r2,
    float* __restrict__ h)
{
    __shared__ __align__(16) float As[64 * 260];
    __shared__ __align__(16) float Ws[256 * 68];
    int tid = threadIdx.x;
    int row0 = blockIdx.x * 64;
#pragma unroll
    for (int q = 0; q < 16; ++q) {               // A: 64 rows x 256 cols
        int e4 = q * 256 + tid;
        int r = e4 >> 6, k4 = (e4 & 63) * 4;
        float4 v;
        if (k4 < 128) v = *(const float4*)(XAg + (size_t)(row0 + r) * D1 + k4);
        else          v = *(const float4*)(Xg + (size_t)(row0 + r) * D1 + (k4 - 128));
        *(float4*)(As + r * 260 + k4) = v;
    }
#pragma unroll
    for (int q = 0; q < 16; ++q) {               // W: 256 k x 64 c
        int e4 = q * 256 + tid;
        int k = e4 >> 4, c4 = (e4 & 15) * 4;
        float4 v;
        if (k < 128) v = *(const float4*)(Wpa + k * D2 + c4);
        else         v = *(const float4*)(Wpn + (k - 128) * D2 + c4);
        *(float4*)(Ws + k * 68 + c4) = v;
    }
    __syncthreads();
    int rl = tid >> 2, cq = (tid & 3) * 16;
    float acc[16];
#pragma unroll
    for (int m = 0; m < 16; ++m) acc[m] = 0.0f;
    for (int k = 0; k < 256; ++k) {
        float a = As[rl * 260 + k];
        float4 w0 = *(const float4*)(Ws + k * 68 + cq);
        float4 w1 = *(const float4*)(Ws + k * 68 + cq + 4);
        float4 w2 = *(const float4*)(Ws + k * 68 + cq + 8);
        float4 w3 = *(const float4*)(Ws + k * 68 + cq + 12);
        acc[0] += a * w0.x;  acc[1] += a * w0.y;  acc[2] += a * w0.z;  acc[3] += a * w0.w;
        acc[4] += a * w1.x;  acc[5] += a * w1.y;  acc[6] += a * w1.z;  acc[7] += a * w1.w;
        acc[8] += a * w2.x;  acc[9] += a * w2.y;  acc[10] += a * w2.z; acc[11] += a * w2.w;
        acc[12] += a * w3.x; acc[13] += a * w3.y; acc[14] += a * w3.z; acc[15] += a * w3.w;
    }
#pragma unroll
    for (int m = 0; m < 16; ++m) {
        int c = cq + m;
        float t = acc[m] + bpa[c] + bpn[c];
        t = (t - m2[c]) * r2[c] * g2[c] + b2[c];
        h[(size_t)(row0 + rl) * D2 + c] = selu_f(t);
    }
}

// ---------------------------------------------------------------------------
// k_head: one wave per batch. scores -> sigmoid -> rank-by-count top-53
// (desc, ties by index = jax.lax.top_k) -> proj -> W_node -> out (256x2 fp32)
// ---------------------------------------------------------------------------
__global__ __launch_bounds__(64) void k_head(
    const float* __restrict__ h, const float* __restrict__ Wpool,
    const float* __restrict__ bpool, const float* __restrict__ Wproj,
    const float* __restrict__ bproj, const float* __restrict__ Wnode,
    const float* __restrict__ bnode, float* __restrict__ out)
{
    __shared__ float sc[NN], pv[NN], sel[NP];
    int lane = threadIdx.x, b = blockIdx.x;
    for (int j = lane; j < NN; j += 64) {
        const float* hr = h + (size_t)(b * NN + j) * D2;
        float z = 0.0f;
        for (int c = 0; c < D2; ++c) z += hr[c] * Wpool[c];
        z += bpool[0];
        float s = 1.0f / (1.0f + expf(-z));
        float q = 0.0f;
        for (int c = 0; c < D2; ++c) q += (hr[c] * s) * Wproj[c];
        q += bproj[0];
        sc[j] = s; pv[j] = q;
    }
    __syncthreads();
    for (int j = lane; j < NN; j += 64) {
        float sj = sc[j]; int rank = 0;
        for (int k = 0; k < NN; ++k) {
            float sk = sc[k];
            rank += (sk > sj) || (sk == sj && k < j);
        }
        if (rank < NP) sel[rank] = pv[j];
    }
    __syncthreads();
    if (lane < 2) {
        float o = 0.0f;
        for (int r = 0; r < NP; ++r) o += sel[r] * Wnode[r * 2 + lane];
        out[b * 2 + lane] = o + bnode[lane];
    }
}

// ---------------------------------------------------------------------------
extern "C" void kernel_launch(void* const* d_in, const int* in_sizes, int n_in,
                              void* d_out, int out_size, void* d_ws, size_t ws_size,
                              hipStream_t stream)
{
    const float* feat  = (const float*)d_in[0];
    const float* Wll   = (const float*)d_in[1];
    const float* bll   = (const float*)d_in[2];
    const float* g1    = (const float*)d_in[3];
    const float* b1    = (const float*)d_in[4];
    const float* m1    = (const float*)d_in[5];
    const float* v1    = (const float*)d_in[6];
    const float* Wap   = (const float*)d_in[7];
    const float* bap   = (const float*)d_in[8];
    const float* attw  = (const float*)d_in[9];
    const float* Wpa   = (const float*)d_in[10];
    const float* bpa   = (const float*)d_in[11];
    const float* Wpn   = (const float*)d_in[12];
    const float* bpn   = (const float*)d_in[13];
    const float* g2    = (const float*)d_in[14];
    const float* b2    = (const float*)d_in[15];
    const float* m2    = (const float*)d_in[16];
    const float* v2    = (const float*)d_in[17];
    const float* Wpool = (const float*)d_in[18];
    const float* bpool = (const float*)d_in[19];
    const float* Wproj = (const float*)d_in[20];
    const float* bproj = (const float*)d_in[21];
    const float* Wnode = (const float*)d_in[22];
    const float* bnode = (const float*)d_in[23];
    float* out = (float*)d_out;

    char* w = (char*)d_ws;
    float* y    = (float*)w; w += (size_t)ROWS1 * D1 * 4;   // 26.3 MB
    float* X    = (float*)w; w += (size_t)ROWS2 * D1 * 4;   // 8.8 MB
    float* XA   = (float*)w; w += (size_t)ROWS2 * D1 * 4;   // 8.8 MB
    float* hbuf = (float*)w; w += (size_t)ROWS2 * D2 * 4;   // 4.4 MB
    float* WllT = (float*)w; w += (size_t)128 * 1024 * 4;
    float* WapT = (float*)w; w += (size_t)64 * 128 * 4;
    float* r1   = (float*)w; w += 128 * 4;
    float* r2   = (float*)w; w += 64 * 4;

    hipLaunchKernelGGL(k_pre,   dim3(545),  dim3(256), 0, stream,
                       Wll, Wap, v1, v2, WllT, WapT, r1, r2);
    hipLaunchKernelGGL(k_gemm1, dim3(804),  dim3(256), 0, stream, feat, WllT, y);
    hipLaunchKernelGGL(k_pool,  dim3(8576), dim3(256), 0, stream,
                       y, bll, g1, b1, m1, r1, X);
    hipLaunchKernelGGL(k_attn,  dim3(256),  dim3(256), 0, stream,
                       X, WapT, bap, attw, XA);
    hipLaunchKernelGGL(k_gemm2, dim3(268),  dim3(256), 0, stream,
                       XA, X, Wpa, Wpn, bpa, bpn, g2, b2, m2, r2, hbuf);
    hipLaunchKernelGGL(k_head,  dim3(256),  dim3(64),  0, stream,
                       hbuf, Wpool, bpool, Wproj, bproj, Wnode, bnode, out);
}

// Round 3
// 1341.499 us; speedup vs baseline: 12.9638x; 12.9638x over previous
//
#include <hip/hip_runtime.h>
#include <stdint.h>
#include <math.h>

// ---------------------------------------------------------------------------
// Model_14104672600612 — fp32 graph-attention pipeline on MI355X (gfx950)
// R3: k_attn rewritten to kill register-spill scratch traffic (R2: 44 GB HBM
// per dispatch, VALUBusy 2.8%, VGPR=256 cap). eacc lives in LDS (cells are
// thread-private in the c-loop -> sync-free), W folded into A-fragment load
// (no Ys phase), k-loop unroll capped at 4. fp32 throughout (no fp32 MFMA on
// CDNA4; fp32 keeps top-k node ranking stable vs the np reference).
// ---------------------------------------------------------------------------

#define BS 256
#define SEQ 201
#define DS 1024
#define D1 128
#define D2 64
#define NN 67
#define NP 53
#define ROWS1 (BS * SEQ)   // 51456
#define ROWS2 (BS * NN)    // 17152

#define SELU_LAM 1.0507009873554805f
#define SELU_ALP 1.6732632423543772f

__device__ __forceinline__ float selu_f(float x) {
    return (x > 0.0f) ? SELU_LAM * x : SELU_LAM * (SELU_ALP * expm1f(x));
}

// ---------------------------------------------------------------------------
// k_pre: WllT[c][k] = Wll[k][c] (128x1024), WapT[c][d] = Wap[d][c] (64x128),
// r1/r2 = 1/sqrt(var+eps).
// ---------------------------------------------------------------------------
__global__ __launch_bounds__(256) void k_pre(
    const float* __restrict__ Wll, const float* __restrict__ Wap,
    const float* __restrict__ v1, const float* __restrict__ v2,
    float* __restrict__ WllT, float* __restrict__ WapT,
    float* __restrict__ r1, float* __restrict__ r2)
{
    int t = blockIdx.x * 256 + threadIdx.x;
    if (t < 131072) {
        int c = t >> 10, k = t & 1023;
        WllT[t] = Wll[k * D1 + c];
    } else if (t < 139264) {
        int i = t - 131072; int c = i >> 7, d = i & 127;
        WapT[i] = Wap[d * D2 + c];
    } else if (t < 139392) {
        int d = t - 139264;
        r1[d] = 1.0f / sqrtf(v1[d] + 1e-5f);
    } else if (t < 139456) {
        int c = t - 139392;
        r2[c] = 1.0f / sqrtf(v2[c] + 1e-5f);
    }
}

// ---------------------------------------------------------------------------
// k_gemm1: y(51456x128) = feat(51456x1024) @ Wll. fp32 tiled 64x128,
// micro-tile 4x8 per thread. (unchanged from R2 — not the bottleneck)
// ---------------------------------------------------------------------------
__global__ __launch_bounds__(256) void k_gemm1(
    const float* __restrict__ A, const float* __restrict__ Bt,
    float* __restrict__ y)
{
    __shared__ __align__(16) float As[64 * 36];
    __shared__ __align__(16) float Bs[128 * 36];
    int tid = threadIdx.x;
    int row0 = blockIdx.x * 64;
    int ty = tid >> 4, tx = tid & 15;
    float acc[4][8];
#pragma unroll
    for (int r = 0; r < 4; ++r)
#pragma unroll
        for (int m = 0; m < 8; ++m) acc[r][m] = 0.0f;

    int si = tid >> 2, sk = (tid & 3) * 8;
    int bc = tid >> 1, bh = (tid & 1) * 16;
    const float* gA = A + (size_t)(row0 + si) * DS + sk;
    const float* gB = Bt + (size_t)bc * DS + bh;

    for (int k0 = 0; k0 < DS; k0 += 32) {
        float4 a0 = *(const float4*)(gA + k0);
        float4 a1 = *(const float4*)(gA + k0 + 4);
        float4 b0 = *(const float4*)(gB + k0);
        float4 b1 = *(const float4*)(gB + k0 + 4);
        float4 b2 = *(const float4*)(gB + k0 + 8);
        float4 b3 = *(const float4*)(gB + k0 + 12);
        __syncthreads();
        *(float4*)(As + si * 36 + sk)      = a0;
        *(float4*)(As + si * 36 + sk + 4)  = a1;
        *(float4*)(Bs + bc * 36 + bh)      = b0;
        *(float4*)(Bs + bc * 36 + bh + 4)  = b1;
        *(float4*)(Bs + bc * 36 + bh + 8)  = b2;
        *(float4*)(Bs + bc * 36 + bh + 12) = b3;
        __syncthreads();
#pragma unroll
        for (int k4 = 0; k4 < 8; ++k4) {
            float4 av[4], bv[8];
#pragma unroll
            for (int r = 0; r < 4; ++r)
                av[r] = *(const float4*)(As + (ty + 16 * r) * 36 + k4 * 4);
#pragma unroll
            for (int m = 0; m < 8; ++m)
                bv[m] = *(const float4*)(Bs + (tx + 16 * m) * 36 + k4 * 4);
#pragma unroll
            for (int r = 0; r < 4; ++r)
#pragma unroll
                for (int m = 0; m < 8; ++m) {
                    acc[r][m] += av[r].x * bv[m].x;
                    acc[r][m] += av[r].y * bv[m].y;
                    acc[r][m] += av[r].z * bv[m].z;
                    acc[r][m] += av[r].w * bv[m].w;
                }
        }
    }
#pragma unroll
    for (int r = 0; r < 4; ++r)
#pragma unroll
        for (int m = 0; m < 8; ++m)
            y[(size_t)(row0 + ty + 16 * r) * D1 + tx + 16 * m] = acc[r][m];
}

// ---------------------------------------------------------------------------
// k_pool: +b_ll, maxpool3 over seq, BN1, SELU -> X (17152x128)
// ---------------------------------------------------------------------------
__global__ __launch_bounds__(256) void k_pool(
    const float* __restrict__ y, const float* __restrict__ bll,
    const float* __restrict__ g1, const float* __restrict__ b1,
    const float* __restrict__ m1, const float* __restrict__ r1,
    float* __restrict__ X)
{
    int t = blockIdx.x * 256 + threadIdx.x;
    int d = t & 127, rem = t >> 7;
    int n = rem % NN, b = rem / NN;
    size_t base = ((size_t)(b * SEQ + 3 * n)) * D1 + d;
    float bl = bll[d];
    float v0 = y[base] + bl;
    float v1v = y[base + D1] + bl;
    float v2v = y[base + 2 * D1] + bl;
    float v = fmaxf(fmaxf(v0, v1v), v2v);
    v = (v - m1[d]) * r1[d] * g1[d] + b1[d];
    X[(size_t)rem * D1 + d] = selu_f(v);
}

// ---------------------------------------------------------------------------
// k_attn (R3): one block (256 thr) per batch b.
//   LDS: Xs[80x132] staged X rows (zero-padded), Ws[64x128] = WapT,
//        e[80x85] cross-c accumulator (cell (i,j) owned by thread
//        (i%16)*16 + (j%16) -> sync-free c-loop).
//   Per c: E[5][5] regs over K=128 with W folded into the A-fragment
//   (ya = xs4 * w4, w4 wave-uniform broadcast); then
//   e[i][j] += tanh(E + bap[c]) * attw[c].
//   Phase 2: softmax per row (thread-per-row). Phase 3: xa = att @ X.
// Register budget in hot loop: E(25) + ya/xv temps(~44) + addr (~15) < 128.
// ---------------------------------------------------------------------------
__global__ __launch_bounds__(256) void k_attn(
    const float* __restrict__ X, const float* __restrict__ WapT,
    const float* __restrict__ bap, const float* __restrict__ attw,
    float* __restrict__ XA)
{
    __shared__ __align__(16) float Xs[80 * 132];   // 42.2 KB
    __shared__ __align__(16) float Ws[64 * 128];   // 32.0 KB
    __shared__ float e[80 * 85];                   // 27.2 KB  (stride 85: coprime w/ 32 banks)
    int tid = threadIdx.x;
    int b = blockIdx.x;
    const float* Xb = X + (size_t)b * NN * D1;

    // stage Xs (rows 67..79 zero), Ws, init e
#pragma unroll
    for (int q = 0; q < 40; ++q) {
        int t = q * 256 + tid;
        int r = t >> 7, d = t & 127;
        Xs[r * 132 + d] = (r < NN) ? Xb[(size_t)r * D1 + d] : 0.0f;
    }
#pragma unroll
    for (int q = 0; q < 32; ++q) {
        int t = q * 256 + tid;
        Ws[t] = WapT[t];
    }
    for (int t = tid; t < 80 * 85; t += 256) e[t] = 0.0f;
    __syncthreads();

    int ti = tid >> 4, tj = tid & 15;

    // ---- phase 1: sync-free accumulation over c ----
    for (int c = 0; c < D2; ++c) {
        float bc = bap[c], ac = attw[c];
        const float* wrow = Ws + c * D1;
        float E[5][5];
#pragma unroll
        for (int a = 0; a < 5; ++a)
#pragma unroll
            for (int m = 0; m < 5; ++m) E[a][m] = 0.0f;
#pragma unroll 4
        for (int k4 = 0; k4 < 32; ++k4) {
            float4 w4 = *(const float4*)(wrow + k4 * 4);   // wave-uniform broadcast
            float4 ya[5], xv[5];
#pragma unroll
            for (int a = 0; a < 5; ++a) {
                float4 xa4 = *(const float4*)(Xs + (ti + 16 * a) * 132 + k4 * 4);
                ya[a].x = xa4.x * w4.x; ya[a].y = xa4.y * w4.y;
                ya[a].z = xa4.z * w4.z; ya[a].w = xa4.w * w4.w;
            }
#pragma unroll
            for (int m = 0; m < 5; ++m)
                xv[m] = *(const float4*)(Xs + (tj + 16 * m) * 132 + k4 * 4);
#pragma unroll
            for (int a = 0; a < 5; ++a)
#pragma unroll
                for (int m = 0; m < 5; ++m) {
                    E[a][m] += ya[a].x * xv[m].x;
                    E[a][m] += ya[a].y * xv[m].y;
                    E[a][m] += ya[a].z * xv[m].z;
                    E[a][m] += ya[a].w * xv[m].w;
                }
        }
#pragma unroll
        for (int a = 0; a < 5; ++a)
#pragma unroll
            for (int m = 0; m < 5; ++m)
                e[(ti + 16 * a) * 85 + (tj + 16 * m)] += tanhf(E[a][m] + bc) * ac;
    }
    __syncthreads();

    // ---- phase 2: softmax over j (thread-per-row, rows 0..66) ----
    if (tid < NN) {
        float* er = e + tid * 85;
        float mx = -1e30f;
        for (int j = 0; j < NN; ++j) mx = fmaxf(mx, er[j]);
        float sum = 0.0f;
        for (int j = 0; j < NN; ++j) { float p = expf(er[j] - mx); er[j] = p; sum += p; }
        float inv = 1.0f / sum;
        for (int j = 0; j < NN; ++j) er[j] *= inv;
    }
    __syncthreads();

    // ---- phase 3: xa[i][d] = sum_j att[i][j] * X[j][d] ----
    int d0 = tj * 8;
    float o[5][8];
#pragma unroll
    for (int a = 0; a < 5; ++a)
#pragma unroll
        for (int dd = 0; dd < 8; ++dd) o[a][dd] = 0.0f;
    for (int j = 0; j < NN; ++j) {
        float4 x0 = *(const float4*)(Xs + j * 132 + d0);
        float4 x1 = *(const float4*)(Xs + j * 132 + d0 + 4);
        float av[5];
#pragma unroll
        for (int a = 0; a < 5; ++a) av[a] = e[(ti + 16 * a) * 85 + j];
#pragma unroll
        for (int a = 0; a < 5; ++a) {
            o[a][0] += av[a] * x0.x; o[a][1] += av[a] * x0.y;
            o[a][2] += av[a] * x0.z; o[a][3] += av[a] * x0.w;
            o[a][4] += av[a] * x1.x; o[a][5] += av[a] * x1.y;
            o[a][6] += av[a] * x1.z; o[a][7] += av[a] * x1.w;
        }
    }
#pragma unroll
    for (int a = 0; a < 5; ++a) {
        int i = ti + 16 * a;
        if (i < NN) {
            float* dst = XA + (size_t)(b * NN + i) * D1 + d0;
            float4 s0, s1;
            s0.x = o[a][0]; s0.y = o[a][1]; s0.z = o[a][2]; s0.w = o[a][3];
            s1.x = o[a][4]; s1.y = o[a][5]; s1.z = o[a][6]; s1.w = o[a][7];
            *(float4*)(dst) = s0;
            *(float4*)(dst + 4) = s1;
        }
    }
}

// ---------------------------------------------------------------------------
// k_gemm2: h = selu(bn2( xa@Wpa + bpa + x@Wpn + bpn )). (unchanged from R2)
// ---------------------------------------------------------------------------
__global__ __launch_bounds__(256) void k_gemm2(
    const float* __restrict__ XAg, const float* __restrict__ Xg,
    const float* __restrict__ Wpa, const float* __restrict__ Wpn,
    const float* __restrict__ bpa, const float* __restrict__ bpn,
    const float* __restrict__ g2, const float* __restrict__ b2,
    const float* __restrict__ m2, const float* __restrict__ r2,
    float* __restrict__ h)
{
    __shared__ __align__(16) float As[64 * 260];
    __shared__ __align__(16) float Ws[256 * 68];
    int tid = threadIdx.x;
    int row0 = blockIdx.x * 64;
#pragma unroll
    for (int q = 0; q < 16; ++q) {
        int e4 = q * 256 + tid;
        int r = e4 >> 6, k4 = (e4 & 63) * 4;
        float4 v;
        if (k4 < 128) v = *(const float4*)(XAg + (size_t)(row0 + r) * D1 + k4);
        else          v = *(const float4*)(Xg + (size_t)(row0 + r) * D1 + (k4 - 128));
        *(float4*)(As + r * 260 + k4) = v;
    }
#pragma unroll
    for (int q = 0; q < 16; ++q) {
        int e4 = q * 256 + tid;
        int k = e4 >> 4, c4 = (e4 & 15) * 4;
        float4 v;
        if (k < 128) v = *(const float4*)(Wpa + k * D2 + c4);
        else         v = *(const float4*)(Wpn + (k - 128) * D2 + c4);
        *(float4*)(Ws + k * 68 + c4) = v;
    }
    __syncthreads();
    int rl = tid >> 2, cq = (tid & 3) * 16;
    float acc[16];
#pragma unroll
    for (int m = 0; m < 16; ++m) acc[m] = 0.0f;
    for (int k = 0; k < 256; ++k) {
        float a = As[rl * 260 + k];
        float4 w0 = *(const float4*)(Ws + k * 68 + cq);
        float4 w1 = *(const float4*)(Ws + k * 68 + cq + 4);
        float4 w2 = *(const float4*)(Ws + k * 68 + cq + 8);
        float4 w3 = *(const float4*)(Ws + k * 68 + cq + 12);
        acc[0] += a * w0.x;  acc[1] += a * w0.y;  acc[2] += a * w0.z;  acc[3] += a * w0.w;
        acc[4] += a * w1.x;  acc[5] += a * w1.y;  acc[6] += a * w1.z;  acc[7] += a * w1.w;
        acc[8] += a * w2.x;  acc[9] += a * w2.y;  acc[10] += a * w2.z; acc[11] += a * w2.w;
        acc[12] += a * w3.x; acc[13] += a * w3.y; acc[14] += a * w3.z; acc[15] += a * w3.w;
    }
#pragma unroll
    for (int m = 0; m < 16; ++m) {
        int c = cq + m;
        float t = acc[m] + bpa[c] + bpn[c];
        t = (t - m2[c]) * r2[c] * g2[c] + b2[c];
        h[(size_t)(row0 + rl) * D2 + c] = selu_f(t);
    }
}

// ---------------------------------------------------------------------------
// k_head: one wave per batch. scores -> sigmoid -> rank-by-count top-53
// (desc, ties by index = jax.lax.top_k) -> proj -> W_node -> out (256x2 fp32)
// ---------------------------------------------------------------------------
__global__ __launch_bounds__(64) void k_head(
    const float* __restrict__ h, const float* __restrict__ Wpool,
    const float* __restrict__ bpool, const float* __restrict__ Wproj,
    const float* __restrict__ bproj, const float* __restrict__ Wnode,
    const float* __restrict__ bnode, float* __restrict__ out)
{
    __shared__ float sc[NN], pv[NN], sel[NP];
    int lane = threadIdx.x, b = blockIdx.x;
    for (int j = lane; j < NN; j += 64) {
        const float* hr = h + (size_t)(b * NN + j) * D2;
        float z = 0.0f;
        for (int c = 0; c < D2; ++c) z += hr[c] * Wpool[c];
        z += bpool[0];
        float s = 1.0f / (1.0f + expf(-z));
        float q = 0.0f;
        for (int c = 0; c < D2; ++c) q += (hr[c] * s) * Wproj[c];
        q += bproj[0];
        sc[j] = s; pv[j] = q;
    }
    __syncthreads();
    for (int j = lane; j < NN; j += 64) {
        float sj = sc[j]; int rank = 0;
        for (int k = 0; k < NN; ++k) {
            float sk = sc[k];
            rank += (sk > sj) || (sk == sj && k < j);
        }
        if (rank < NP) sel[rank] = pv[j];
    }
    __syncthreads();
    if (lane < 2) {
        float o = 0.0f;
        for (int r = 0; r < NP; ++r) o += sel[r] * Wnode[r * 2 + lane];
        out[b * 2 + lane] = o + bnode[lane];
    }
}

// ---------------------------------------------------------------------------
extern "C" void kernel_launch(void* const* d_in, const int* in_sizes, int n_in,
                              void* d_out, int out_size, void* d_ws, size_t ws_size,
                              hipStream_t stream)
{
    const float* feat  = (const float*)d_in[0];
    const float* Wll   = (const float*)d_in[1];
    const float* bll   = (const float*)d_in[2];
    const float* g1    = (const float*)d_in[3];
    const float* b1    = (const float*)d_in[4];
    const float* m1    = (const float*)d_in[5];
    const float* v1    = (const float*)d_in[6];
    const float* Wap   = (const float*)d_in[7];
    const float* bap   = (const float*)d_in[8];
    const float* attw  = (const float*)d_in[9];
    const float* Wpa   = (const float*)d_in[10];
    const float* bpa   = (const float*)d_in[11];
    const float* Wpn   = (const float*)d_in[12];
    const float* bpn   = (const float*)d_in[13];
    const float* g2    = (const float*)d_in[14];
    const float* b2    = (const float*)d_in[15];
    const float* m2    = (const float*)d_in[16];
    const float* v2    = (const float*)d_in[17];
    const float* Wpool = (const float*)d_in[18];
    const float* bpool = (const float*)d_in[19];
    const float* Wproj = (const float*)d_in[20];
    const float* bproj = (const float*)d_in[21];
    const float* Wnode = (const float*)d_in[22];
    const float* bnode = (const float*)d_in[23];
    float* out = (float*)d_out;

    char* w = (char*)d_ws;
    float* y    = (float*)w; w += (size_t)ROWS1 * D1 * 4;
    float* X    = (float*)w; w += (size_t)ROWS2 * D1 * 4;
    float* XA   = (float*)w; w += (size_t)ROWS2 * D1 * 4;
    float* hbuf = (float*)w; w += (size_t)ROWS2 * D2 * 4;
    float* WllT = (float*)w; w += (size_t)128 * 1024 * 4;
    float* WapT = (float*)w; w += (size_t)64 * 128 * 4;
    float* r1   = (float*)w; w += 128 * 4;
    float* r2   = (float*)w; w += 64 * 4;

    hipLaunchKernelGGL(k_pre,   dim3(545),  dim3(256), 0, stream,
                       Wll, Wap, v1, v2, WllT, WapT, r1, r2);
    hipLaunchKernelGGL(k_gemm1, dim3(804),  dim3(256), 0, stream, feat, WllT, y);
    hipLaunchKernelGGL(k_pool,  dim3(8576), dim3(256), 0, stream,
                       y, bll, g1, b1, m1, r1, X);
    hipLaunchKernelGGL(k_attn,  dim3(256),  dim3(256), 0, stream,
                       X, WapT, bap, attw, XA);
    hipLaunchKernelGGL(k_gemm2, dim3(268),  dim3(256), 0, stream,
                       XA, X, Wpa, Wpn, bpa, bpn, g2, b2, m2, r2, hbuf);
    hipLaunchKernelGGL(k_head,  dim3(256),  dim3(64),  0, stream,
                       hbuf, Wpool, bpool, Wproj, bproj, Wnode, bnode, out);
}

// Round 4
// 1008.070 us; speedup vs baseline: 17.2517x; 1.3308x over previous
//
#include <hip/hip_runtime.h>
#include <stdint.h>
#include <math.h>

// ---------------------------------------------------------------------------
// Model_14104672600612 — fp32 graph-attention pipeline on MI355X (gfx950)
// R4: k_attn phase-1 restructured. R3 counters: VALUBusy 57%, occupancy
// 1 block/CU, LDS-read-bound (11 ds_read_b128 per c per k4, re-reading the
// same X fragments for all 64 c). Changes:
//   (1) c-blocking C=4: E_c = sum_k (X[i,k]X[j,k]) W[k,c]; pair product
//       computed once per k, FMA'd into 4 c-accumulators.
//   (2) W_ap/bap/attw read via wave-uniform global loads (scalar path) —
//       Ws LDS bank removed (102->69 KB).
//   (3) symmetry: e[i][j]==e[j][i]; compute supercells a<=m only (15/25),
//       mirror-write. Unique owner per cell -> race-free, same c-order ->
//       bit-identical results.
//   (4) cross-c accumulator eacc kept in registers.
// ---------------------------------------------------------------------------

#define BS 256
#define SEQ 201
#define DS 1024
#define D1 128
#define D2 64
#define NN 67
#define NP 53
#define ROWS1 (BS * SEQ)   // 51456
#define ROWS2 (BS * NN)    // 17152

#define SELU_LAM 1.0507009873554805f
#define SELU_ALP 1.6732632423543772f

__device__ __forceinline__ float selu_f(float x) {
    return (x > 0.0f) ? SELU_LAM * x : SELU_LAM * (SELU_ALP * expm1f(x));
}

__device__ __forceinline__ float fc(float4 v, int k) {
    switch (k & 3) {
        case 0: return v.x;
        case 1: return v.y;
        case 2: return v.z;
        default: return v.w;
    }
}

// ---------------------------------------------------------------------------
// k_pre: WllT[c][k] = Wll[k][c] (128x1024), WapT[c][d] = Wap[d][c] (64x128),
// r1/r2 = 1/sqrt(var+eps).
// ---------------------------------------------------------------------------
__global__ __launch_bounds__(256) void k_pre(
    const float* __restrict__ Wll, const float* __restrict__ Wap,
    const float* __restrict__ v1, const float* __restrict__ v2,
    float* __restrict__ WllT, float* __restrict__ WapT,
    float* __restrict__ r1, float* __restrict__ r2)
{
    int t = blockIdx.x * 256 + threadIdx.x;
    if (t < 131072) {
        int c = t >> 10, k = t & 1023;
        WllT[t] = Wll[k * D1 + c];
    } else if (t < 139264) {
        int i = t - 131072; int c = i >> 7, d = i & 127;
        WapT[i] = Wap[d * D2 + c];
    } else if (t < 139392) {
        int d = t - 139264;
        r1[d] = 1.0f / sqrtf(v1[d] + 1e-5f);
    } else if (t < 139456) {
        int c = t - 139392;
        r2[c] = 1.0f / sqrtf(v2[c] + 1e-5f);
    }
}

// ---------------------------------------------------------------------------
// k_gemm1: y(51456x128) = feat(51456x1024) @ Wll. fp32 tiled 64x128,
// micro-tile 4x8 per thread. (unchanged — revisit after k_attn is fixed)
// ---------------------------------------------------------------------------
__global__ __launch_bounds__(256) void k_gemm1(
    const float* __restrict__ A, const float* __restrict__ Bt,
    float* __restrict__ y)
{
    __shared__ __align__(16) float As[64 * 36];
    __shared__ __align__(16) float Bs[128 * 36];
    int tid = threadIdx.x;
    int row0 = blockIdx.x * 64;
    int ty = tid >> 4, tx = tid & 15;
    float acc[4][8];
#pragma unroll
    for (int r = 0; r < 4; ++r)
#pragma unroll
        for (int m = 0; m < 8; ++m) acc[r][m] = 0.0f;

    int si = tid >> 2, sk = (tid & 3) * 8;
    int bc = tid >> 1, bh = (tid & 1) * 16;
    const float* gA = A + (size_t)(row0 + si) * DS + sk;
    const float* gB = Bt + (size_t)bc * DS + bh;

    for (int k0 = 0; k0 < DS; k0 += 32) {
        float4 a0 = *(const float4*)(gA + k0);
        float4 a1 = *(const float4*)(gA + k0 + 4);
        float4 b0 = *(const float4*)(gB + k0);
        float4 b1 = *(const float4*)(gB + k0 + 4);
        float4 b2 = *(const float4*)(gB + k0 + 8);
        float4 b3 = *(const float4*)(gB + k0 + 12);
        __syncthreads();
        *(float4*)(As + si * 36 + sk)      = a0;
        *(float4*)(As + si * 36 + sk + 4)  = a1;
        *(float4*)(Bs + bc * 36 + bh)      = b0;
        *(float4*)(Bs + bc * 36 + bh + 4)  = b1;
        *(float4*)(Bs + bc * 36 + bh + 8)  = b2;
        *(float4*)(Bs + bc * 36 + bh + 12) = b3;
        __syncthreads();
#pragma unroll
        for (int k4 = 0; k4 < 8; ++k4) {
            float4 av[4], bv[8];
#pragma unroll
            for (int r = 0; r < 4; ++r)
                av[r] = *(const float4*)(As + (ty + 16 * r) * 36 + k4 * 4);
#pragma unroll
            for (int m = 0; m < 8; ++m)
                bv[m] = *(const float4*)(Bs + (tx + 16 * m) * 36 + k4 * 4);
#pragma unroll
            for (int r = 0; r < 4; ++r)
#pragma unroll
                for (int m = 0; m < 8; ++m) {
                    acc[r][m] += av[r].x * bv[m].x;
                    acc[r][m] += av[r].y * bv[m].y;
                    acc[r][m] += av[r].z * bv[m].z;
                    acc[r][m] += av[r].w * bv[m].w;
                }
        }
    }
#pragma unroll
    for (int r = 0; r < 4; ++r)
#pragma unroll
        for (int m = 0; m < 8; ++m)
            y[(size_t)(row0 + ty + 16 * r) * D1 + tx + 16 * m] = acc[r][m];
}

// ---------------------------------------------------------------------------
// k_pool: +b_ll, maxpool3 over seq, BN1, SELU -> X (17152x128)
// ---------------------------------------------------------------------------
__global__ __launch_bounds__(256) void k_pool(
    const float* __restrict__ y, const float* __restrict__ bll,
    const float* __restrict__ g1, const float* __restrict__ b1,
    const float* __restrict__ m1, const float* __restrict__ r1,
    float* __restrict__ X)
{
    int t = blockIdx.x * 256 + threadIdx.x;
    int d = t & 127, rem = t >> 7;
    int n = rem % NN, b = rem / NN;
    size_t base = ((size_t)(b * SEQ + 3 * n)) * D1 + d;
    float bl = bll[d];
    float v0 = y[base] + bl;
    float v1v = y[base + D1] + bl;
    float v2v = y[base + 2 * D1] + bl;
    float v = fmaxf(fmaxf(v0, v1v), v2v);
    v = (v - m1[d]) * r1[d] * g1[d] + b1[d];
    X[(size_t)rem * D1 + d] = selu_f(v);
}

// ---------------------------------------------------------------------------
// k_attn (R4): one block (256 thr) per batch b.
// LDS: Xs[80x132] (zero-padded X rows), e[80x85] logits. 69.4 KB total.
// Phase 1: thread (ti,tj) owns cells (ti+16a, tj+16m) for a<=m (15 cells).
//   c-group loop (4 c at a time): E[a][m][c] over K=128; pair product
//   P = X[i,k]*X[j,k] shared across the 4 c-FMAs. W rows read from global
//   (wave-uniform -> scalar loads). Then eacc[a][m] += tanh(E+b_c)*a_c in
//   registers; finally written (+ mirror for a<m) to e.
// Phase 2: softmax per row. Phase 3: xa = att @ X.
// ---------------------------------------------------------------------------
__global__ __launch_bounds__(256, 1) void k_attn(
    const float* __restrict__ X, const float* __restrict__ WapT,
    const float* __restrict__ bap, const float* __restrict__ attw,
    float* __restrict__ XA)
{
    __shared__ __align__(16) float Xs[80 * 132];   // 42.2 KB
    __shared__ float e[80 * 85];                   // 27.2 KB (stride 85)
    int tid = threadIdx.x;
    int b = blockIdx.x;
    const float* Xb = X + (size_t)b * NN * D1;

#pragma unroll
    for (int q = 0; q < 40; ++q) {
        int t = q * 256 + tid;
        int r = t >> 7, d = t & 127;
        Xs[r * 132 + d] = (r < NN) ? Xb[(size_t)r * D1 + d] : 0.0f;
    }
    __syncthreads();

    int ti = tid >> 4, tj = tid & 15;

    // ---- phase 1 ----
    float eacc[5][5];
#pragma unroll
    for (int a = 0; a < 5; ++a)
#pragma unroll
        for (int m = a; m < 5; ++m) eacc[a][m] = 0.0f;

    for (int cg = 0; cg < 16; ++cg) {
        float E[5][5][4];
#pragma unroll
        for (int a = 0; a < 5; ++a)
#pragma unroll
            for (int m = a; m < 5; ++m)
#pragma unroll
                for (int c = 0; c < 4; ++c) E[a][m][c] = 0.0f;

#pragma unroll 2
        for (int k4 = 0; k4 < 32; ++k4) {
            float4 xa[5], xv[5], w[4];
#pragma unroll
            for (int a = 0; a < 5; ++a)
                xa[a] = *(const float4*)(Xs + (ti + 16 * a) * 132 + k4 * 4);
#pragma unroll
            for (int m = 0; m < 5; ++m)
                xv[m] = *(const float4*)(Xs + (tj + 16 * m) * 132 + k4 * 4);
#pragma unroll
            for (int c = 0; c < 4; ++c)
                w[c] = *(const float4*)(WapT + (cg * 4 + c) * D1 + k4 * 4);
#pragma unroll
            for (int kk = 0; kk < 4; ++kk) {
#pragma unroll
                for (int a = 0; a < 5; ++a) {
                    float pa = fc(xa[a], kk);
#pragma unroll
                    for (int m = a; m < 5; ++m) {
                        float P = pa * fc(xv[m], kk);
                        E[a][m][0] += P * fc(w[0], kk);
                        E[a][m][1] += P * fc(w[1], kk);
                        E[a][m][2] += P * fc(w[2], kk);
                        E[a][m][3] += P * fc(w[3], kk);
                    }
                }
            }
        }
#pragma unroll
        for (int c = 0; c < 4; ++c) {
            float bc = bap[cg * 4 + c], ac = attw[cg * 4 + c];
#pragma unroll
            for (int a = 0; a < 5; ++a)
#pragma unroll
                for (int m = a; m < 5; ++m)
                    eacc[a][m] += tanhf(E[a][m][c] + bc) * ac;
        }
    }
#pragma unroll
    for (int a = 0; a < 5; ++a)
#pragma unroll
        for (int m = a; m < 5; ++m) {
            int i = ti + 16 * a, j = tj + 16 * m;
            e[i * 85 + j] = eacc[a][m];
            if (a < m) e[j * 85 + i] = eacc[a][m];
        }
    __syncthreads();

    // ---- phase 2: softmax over j (thread-per-row, rows 0..66) ----
    if (tid < NN) {
        float* er = e + tid * 85;
        float mx = -1e30f;
        for (int j = 0; j < NN; ++j) mx = fmaxf(mx, er[j]);
        float sum = 0.0f;
        for (int j = 0; j < NN; ++j) { float p = expf(er[j] - mx); er[j] = p; sum += p; }
        float inv = 1.0f / sum;
        for (int j = 0; j < NN; ++j) er[j] *= inv;
    }
    __syncthreads();

    // ---- phase 3: xa[i][d] = sum_j att[i][j] * X[j][d] ----
    int d0 = tj * 8;
    float o[5][8];
#pragma unroll
    for (int a = 0; a < 5; ++a)
#pragma unroll
        for (int dd = 0; dd < 8; ++dd) o[a][dd] = 0.0f;
    for (int j = 0; j < NN; ++j) {
        float4 x0 = *(const float4*)(Xs + j * 132 + d0);
        float4 x1 = *(const float4*)(Xs + j * 132 + d0 + 4);
        float av[5];
#pragma unroll
        for (int a = 0; a < 5; ++a) av[a] = e[(ti + 16 * a) * 85 + j];
#pragma unroll
        for (int a = 0; a < 5; ++a) {
            o[a][0] += av[a] * x0.x; o[a][1] += av[a] * x0.y;
            o[a][2] += av[a] * x0.z; o[a][3] += av[a] * x0.w;
            o[a][4] += av[a] * x1.x; o[a][5] += av[a] * x1.y;
            o[a][6] += av[a] * x1.z; o[a][7] += av[a] * x1.w;
        }
    }
#pragma unroll
    for (int a = 0; a < 5; ++a) {
        int i = ti + 16 * a;
        if (i < NN) {
            float* dst = XA + (size_t)(b * NN + i) * D1 + d0;
            float4 s0, s1;
            s0.x = o[a][0]; s0.y = o[a][1]; s0.z = o[a][2]; s0.w = o[a][3];
            s1.x = o[a][4]; s1.y = o[a][5]; s1.z = o[a][6]; s1.w = o[a][7];
            *(float4*)(dst) = s0;
            *(float4*)(dst + 4) = s1;
        }
    }
}

// ---------------------------------------------------------------------------
// k_gemm2: h = selu(bn2( xa@Wpa + bpa + x@Wpn + bpn )). (unchanged)
// ---------------------------------------------------------------------------
__global__ __launch_bounds__(256) void k_gemm2(
    const float* __restrict__ XAg, const float* __restrict__ Xg,
    const float* __restrict__ Wpa, const float* __restrict__ Wpn,
    const float* __restrict__ bpa, const float* __restrict__ bpn,
    const float* __restrict__ g2, const float* __restrict__ b2,
    const float* __restrict__ m2, const float* __restrict__ r2,
    float* __restrict__ h)
{
    __shared__ __align__(16) float As[64 * 260];
    __shared__ __align__(16) float Ws[256 * 68];
    int tid = threadIdx.x;
    int row0 = blockIdx.x * 64;
#pragma unroll
    for (int q = 0; q < 16; ++q) {
        int e4 = q * 256 + tid;
        int r = e4 >> 6, k4 = (e4 & 63) * 4;
        float4 v;
        if (k4 < 128) v = *(const float4*)(XAg + (size_t)(row0 + r) * D1 + k4);
        else          v = *(const float4*)(Xg + (size_t)(row0 + r) * D1 + (k4 - 128));
        *(float4*)(As + r * 260 + k4) = v;
    }
#pragma unroll
    for (int q = 0; q < 16; ++q) {
        int e4 = q * 256 + tid;
        int k = e4 >> 4, c4 = (e4 & 15) * 4;
        float4 v;
        if (k < 128) v = *(const float4*)(Wpa + k * D2 + c4);
        else         v = *(const float4*)(Wpn + (k - 128) * D2 + c4);
        *(float4*)(Ws + k * 68 + c4) = v;
    }
    __syncthreads();
    int rl = tid >> 2, cq = (tid & 3) * 16;
    float acc[16];
#pragma unroll
    for (int m = 0; m < 16; ++m) acc[m] = 0.0f;
    for (int k = 0; k < 256; ++k) {
        float a = As[rl * 260 + k];
        float4 w0 = *(const float4*)(Ws + k * 68 + cq);
        float4 w1 = *(const float4*)(Ws + k * 68 + cq + 4);
        float4 w2 = *(const float4*)(Ws + k * 68 + cq + 8);
        float4 w3 = *(const float4*)(Ws + k * 68 + cq + 12);
        acc[0] += a * w0.x;  acc[1] += a * w0.y;  acc[2] += a * w0.z;  acc[3] += a * w0.w;
        acc[4] += a * w1.x;  acc[5] += a * w1.y;  acc[6] += a * w1.z;  acc[7] += a * w1.w;
        acc[8] += a * w2.x;  acc[9] += a * w2.y;  acc[10] += a * w2.z; acc[11] += a * w2.w;
        acc[12] += a * w3.x; acc[13] += a * w3.y; acc[14] += a * w3.z; acc[15] += a * w3.w;
    }
#pragma unroll
    for (int m = 0; m < 16; ++m) {
        int c = cq + m;
        float t = acc[m] + bpa[c] + bpn[c];
        t = (t - m2[c]) * r2[c] * g2[c] + b2[c];
        h[(size_t)(row0 + rl) * D2 + c] = selu_f(t);
    }
}

// ---------------------------------------------------------------------------
// k_head: one wave per batch. scores -> sigmoid -> rank-by-count top-53
// (desc, ties by index = jax.lax.top_k) -> proj -> W_node -> out (256x2 fp32)
// ---------------------------------------------------------------------------
__global__ __launch_bounds__(64) void k_head(
    const float* __restrict__ h, const float* __restrict__ Wpool,
    const float* __restrict__ bpool, const float* __restrict__ Wproj,
    const float* __restrict__ bproj, const float* __restrict__ Wnode,
    const float* __restrict__ bnode, float* __restrict__ out)
{
    __shared__ float sc[NN], pv[NN], sel[NP];
    int lane = threadIdx.x, b = blockIdx.x;
    for (int j = lane; j < NN; j += 64) {
        const float* hr = h + (size_t)(b * NN + j) * D2;
        float z = 0.0f;
        for (int c = 0; c < D2; ++c) z += hr[c] * Wpool[c];
        z += bpool[0];
        float s = 1.0f / (1.0f + expf(-z));
        float q = 0.0f;
        for (int c = 0; c < D2; ++c) q += (hr[c] * s) * Wproj[c];
        q += bproj[0];
        sc[j] = s; pv[j] = q;
    }
    __syncthreads();
    for (int j = lane; j < NN; j += 64) {
        float sj = sc[j]; int rank = 0;
        for (int k = 0; k < NN; ++k) {
            float sk = sc[k];
            rank += (sk > sj) || (sk == sj && k < j);
        }
        if (rank < NP) sel[rank] = pv[j];
    }
    __syncthreads();
    if (lane < 2) {
        float o = 0.0f;
        for (int r = 0; r < NP; ++r) o += sel[r] * Wnode[r * 2 + lane];
        out[b * 2 + lane] = o + bnode[lane];
    }
}

// ---------------------------------------------------------------------------
extern "C" void kernel_launch(void* const* d_in, const int* in_sizes, int n_in,
                              void* d_out, int out_size, void* d_ws, size_t ws_size,
                              hipStream_t stream)
{
    const float* feat  = (const float*)d_in[0];
    const float* Wll   = (const float*)d_in[1];
    const float* bll   = (const float*)d_in[2];
    const float* g1    = (const float*)d_in[3];
    const float* b1    = (const float*)d_in[4];
    const float* m1    = (const float*)d_in[5];
    const float* v1    = (const float*)d_in[6];
    const float* Wap   = (const float*)d_in[7];
    const float* bap   = (const float*)d_in[8];
    const float* attw  = (const float*)d_in[9];
    const float* Wpa   = (const float*)d_in[10];
    const float* bpa   = (const float*)d_in[11];
    const float* Wpn   = (const float*)d_in[12];
    const float* bpn   = (const float*)d_in[13];
    const float* g2    = (const float*)d_in[14];
    const float* b2    = (const float*)d_in[15];
    const float* m2    = (const float*)d_in[16];
    const float* v2    = (const float*)d_in[17];
    const float* Wpool = (const float*)d_in[18];
    const float* bpool = (const float*)d_in[19];
    const float* Wproj = (const float*)d_in[20];
    const float* bproj = (const float*)d_in[21];
    const float* Wnode = (const float*)d_in[22];
    const float* bnode = (const float*)d_in[23];
    float* out = (float*)d_out;

    char* w = (char*)d_ws;
    float* y    = (float*)w; w += (size_t)ROWS1 * D1 * 4;
    float* X    = (float*)w; w += (size_t)ROWS2 * D1 * 4;
    float* XA   = (float*)w; w += (size_t)ROWS2 * D1 * 4;
    float* hbuf = (float*)w; w += (size_t)ROWS2 * D2 * 4;
    float* WllT = (float*)w; w += (size_t)128 * 1024 * 4;
    float* WapT = (float*)w; w += (size_t)64 * 128 * 4;
    float* r1   = (float*)w; w += 128 * 4;
    float* r2   = (float*)w; w += 64 * 4;

    hipLaunchKernelGGL(k_pre,   dim3(545),  dim3(256), 0, stream,
                       Wll, Wap, v1, v2, WllT, WapT, r1, r2);
    hipLaunchKernelGGL(k_gemm1, dim3(804),  dim3(256), 0, stream, feat, WllT, y);
    hipLaunchKernelGGL(k_pool,  dim3(8576), dim3(256), 0, stream,
                       y, bll, g1, b1, m1, r1, X);
    hipLaunchKernelGGL(k_attn,  dim3(256),  dim3(256), 0, stream,
                       X, WapT, bap, attw, XA);
    hipLaunchKernelGGL(k_gemm2, dim3(268),  dim3(256), 0, stream,
                       XA, X, Wpa, Wpn, bpa, bpn, g2, b2, m2, r2, hbuf);
    hipLaunchKernelGGL(k_head,  dim3(256),  dim3(64),  0, stream,
                       hbuf, Wpool, bpool, Wproj, bproj, Wnode, bnode, out);
}

// Round 5
// 810.784 us; speedup vs baseline: 21.4495x; 1.2433x over previous
//
#include <hip/hip_runtime.h>
#include <stdint.h>
#include <math.h>

// ---------------------------------------------------------------------------
// Model_14104672600612 — fp32 graph-attention pipeline on MI355X (gfx950)
// R5: R4 post-mortem showed k_attn was GRID-limited (256 blocks = 1/CU,
// 1 wave/SIMD, VALUBusy 49%). Split k_attn into:
//   k_attn1 (512 blocks = batch x c-half, Xs-only LDS 42 KB, partial logits
//            to global epart aliased on dead y buffer)
//   k_attn2 (256 blocks: sum partials + softmax + att@X)
// k_gemm1 upgraded to 128x128 tile / 8x8 micro-tile (LDS reads per FMA
// halved). fp32 throughout (no fp32 MFMA on CDNA4; keeps top-k rank stable).
// ---------------------------------------------------------------------------

#define BS 256
#define SEQ 201
#define DS 1024
#define D1 128
#define D2 64
#define NN 67
#define NP 53
#define ROWS1 (BS * SEQ)   // 51456
#define ROWS2 (BS * NN)    // 17152

#define SELU_LAM 1.0507009873554805f
#define SELU_ALP 1.6732632423543772f

__device__ __forceinline__ float selu_f(float x) {
    return (x > 0.0f) ? SELU_LAM * x : SELU_LAM * (SELU_ALP * expm1f(x));
}

__device__ __forceinline__ float fc(float4 v, int k) {
    switch (k & 3) {
        case 0: return v.x;
        case 1: return v.y;
        case 2: return v.z;
        default: return v.w;
    }
}

// ---------------------------------------------------------------------------
// k_pre: WllT[c][k] = Wll[k][c] (128x1024), WapT[c][d] = Wap[d][c] (64x128),
// r1/r2 = 1/sqrt(var+eps).
// ---------------------------------------------------------------------------
__global__ __launch_bounds__(256) void k_pre(
    const float* __restrict__ Wll, const float* __restrict__ Wap,
    const float* __restrict__ v1, const float* __restrict__ v2,
    float* __restrict__ WllT, float* __restrict__ WapT,
    float* __restrict__ r1, float* __restrict__ r2)
{
    int t = blockIdx.x * 256 + threadIdx.x;
    if (t < 131072) {
        int c = t >> 10, k = t & 1023;
        WllT[t] = Wll[k * D1 + c];
    } else if (t < 139264) {
        int i = t - 131072; int c = i >> 7, d = i & 127;
        WapT[i] = Wap[d * D2 + c];
    } else if (t < 139392) {
        int d = t - 139264;
        r1[d] = 1.0f / sqrtf(v1[d] + 1e-5f);
    } else if (t < 139456) {
        int c = t - 139392;
        r2[c] = 1.0f / sqrtf(v2[c] + 1e-5f);
    }
}

// ---------------------------------------------------------------------------
// k_gemm1 (R5): y(51456x128) = feat @ Wll. 128x128 tile, BK=32, 8x8
// micro-tile per thread (256 thr). 402 blocks.
// ---------------------------------------------------------------------------
__global__ __launch_bounds__(256) void k_gemm1(
    const float* __restrict__ A, const float* __restrict__ Bt,
    float* __restrict__ y)
{
    __shared__ __align__(16) float As[128 * 36];
    __shared__ __align__(16) float Bs[128 * 36];
    int tid = threadIdx.x;
    int row0 = blockIdx.x * 128;
    int ty = tid >> 4, tx = tid & 15;
    float acc[8][8];
#pragma unroll
    for (int r = 0; r < 8; ++r)
#pragma unroll
        for (int m = 0; m < 8; ++m) acc[r][m] = 0.0f;

    int lr = tid >> 1, lc = (tid & 1) * 16;     // stage: row lr, cols lc..lc+15
    const float* gA = A + (size_t)(row0 + lr) * DS + lc;
    const float* gB = Bt + (size_t)lr * DS + lc;
    float* wa = As + lr * 36 + lc;
    float* wb = Bs + lr * 36 + lc;

    for (int k0 = 0; k0 < DS; k0 += 32) {
        float4 a0 = *(const float4*)(gA + k0);
        float4 a1 = *(const float4*)(gA + k0 + 4);
        float4 a2 = *(const float4*)(gA + k0 + 8);
        float4 a3 = *(const float4*)(gA + k0 + 12);
        float4 b0 = *(const float4*)(gB + k0);
        float4 b1 = *(const float4*)(gB + k0 + 4);
        float4 b2 = *(const float4*)(gB + k0 + 8);
        float4 b3 = *(const float4*)(gB + k0 + 12);
        __syncthreads();
        *(float4*)(wa)      = a0; *(float4*)(wa + 4)  = a1;
        *(float4*)(wa + 8)  = a2; *(float4*)(wa + 12) = a3;
        *(float4*)(wb)      = b0; *(float4*)(wb + 4)  = b1;
        *(float4*)(wb + 8)  = b2; *(float4*)(wb + 12) = b3;
        __syncthreads();
#pragma unroll
        for (int k4 = 0; k4 < 8; ++k4) {
            float4 av[8], bv[8];
#pragma unroll
            for (int r = 0; r < 8; ++r)
                av[r] = *(const float4*)(As + (ty + 16 * r) * 36 + k4 * 4);
#pragma unroll
            for (int m = 0; m < 8; ++m)
                bv[m] = *(const float4*)(Bs + (tx + 16 * m) * 36 + k4 * 4);
#pragma unroll
            for (int r = 0; r < 8; ++r)
#pragma unroll
                for (int m = 0; m < 8; ++m) {
                    acc[r][m] += av[r].x * bv[m].x;
                    acc[r][m] += av[r].y * bv[m].y;
                    acc[r][m] += av[r].z * bv[m].z;
                    acc[r][m] += av[r].w * bv[m].w;
                }
        }
    }
#pragma unroll
    for (int r = 0; r < 8; ++r)
#pragma unroll
        for (int m = 0; m < 8; ++m)
            y[(size_t)(row0 + ty + 16 * r) * D1 + tx + 16 * m] = acc[r][m];
}

// ---------------------------------------------------------------------------
// k_pool: +b_ll, maxpool3 over seq, BN1, SELU -> X (17152x128)
// ---------------------------------------------------------------------------
__global__ __launch_bounds__(256) void k_pool(
    const float* __restrict__ y, const float* __restrict__ bll,
    const float* __restrict__ g1, const float* __restrict__ b1,
    const float* __restrict__ m1, const float* __restrict__ r1,
    float* __restrict__ X)
{
    int t = blockIdx.x * 256 + threadIdx.x;
    int d = t & 127, rem = t >> 7;
    int n = rem % NN, b = rem / NN;
    size_t base = ((size_t)(b * SEQ + 3 * n)) * D1 + d;
    float bl = bll[d];
    float v0 = y[base] + bl;
    float v1v = y[base + D1] + bl;
    float v2v = y[base + 2 * D1] + bl;
    float v = fmaxf(fmaxf(v0, v1v), v2v);
    v = (v - m1[d]) * r1[d] * g1[d] + b1[d];
    X[(size_t)rem * D1 + d] = selu_f(v);
}

// ---------------------------------------------------------------------------
// k_attn1 (R5): 512 blocks = (batch b = blk>>1, c-half z = blk&1).
// LDS: Xs[80x132] only (42.2 KB). Thread (ti,tj) owns supercells a<=m.
// Accumulates eacc over cg in [8z, 8z+8); writes symmetric partial tile to
// epart[blk][80][80] (global, aliased on dead y buffer).
// ---------------------------------------------------------------------------
__global__ __launch_bounds__(256) void k_attn1(
    const float* __restrict__ X, const float* __restrict__ WapT,
    const float* __restrict__ bap, const float* __restrict__ attw,
    float* __restrict__ epart)
{
    __shared__ __align__(16) float Xs[80 * 132];   // 42.2 KB
    int tid = threadIdx.x;
    int blk = blockIdx.x;
    int b = blk >> 1, z = blk & 1;
    const float* Xb = X + (size_t)b * NN * D1;

#pragma unroll
    for (int q = 0; q < 40; ++q) {
        int t = q * 256 + tid;
        int r = t >> 7, d = t & 127;
        Xs[r * 132 + d] = (r < NN) ? Xb[(size_t)r * D1 + d] : 0.0f;
    }
    __syncthreads();

    int ti = tid >> 4, tj = tid & 15;

    float eacc[5][5];
#pragma unroll
    for (int a = 0; a < 5; ++a)
#pragma unroll
        for (int m = a; m < 5; ++m) eacc[a][m] = 0.0f;

    for (int cg = z * 8; cg < z * 8 + 8; ++cg) {
        float E[5][5][4];
#pragma unroll
        for (int a = 0; a < 5; ++a)
#pragma unroll
            for (int m = a; m < 5; ++m)
#pragma unroll
                for (int c = 0; c < 4; ++c) E[a][m][c] = 0.0f;

#pragma unroll 2
        for (int k4 = 0; k4 < 32; ++k4) {
            float4 xa[5], xv[5], w[4];
#pragma unroll
            for (int a = 0; a < 5; ++a)
                xa[a] = *(const float4*)(Xs + (ti + 16 * a) * 132 + k4 * 4);
#pragma unroll
            for (int m = 0; m < 5; ++m)
                xv[m] = *(const float4*)(Xs + (tj + 16 * m) * 132 + k4 * 4);
#pragma unroll
            for (int c = 0; c < 4; ++c)
                w[c] = *(const float4*)(WapT + (cg * 4 + c) * D1 + k4 * 4);
#pragma unroll
            for (int kk = 0; kk < 4; ++kk) {
#pragma unroll
                for (int a = 0; a < 5; ++a) {
                    float pa = fc(xa[a], kk);
#pragma unroll
                    for (int m = a; m < 5; ++m) {
                        float P = pa * fc(xv[m], kk);
                        E[a][m][0] += P * fc(w[0], kk);
                        E[a][m][1] += P * fc(w[1], kk);
                        E[a][m][2] += P * fc(w[2], kk);
                        E[a][m][3] += P * fc(w[3], kk);
                    }
                }
            }
        }
#pragma unroll
        for (int c = 0; c < 4; ++c) {
            float bc = bap[cg * 4 + c], ac = attw[cg * 4 + c];
#pragma unroll
            for (int a = 0; a < 5; ++a)
#pragma unroll
                for (int m = a; m < 5; ++m)
                    eacc[a][m] += tanhf(E[a][m][c] + bc) * ac;
        }
    }

    float* ep = epart + (size_t)blk * 6400;
#pragma unroll
    for (int a = 0; a < 5; ++a)
#pragma unroll
        for (int m = a; m < 5; ++m) {
            int i = ti + 16 * a, j = tj + 16 * m;
            ep[i * 80 + j] = eacc[a][m];
            if (a < m) ep[j * 80 + i] = eacc[a][m];
        }
}

// ---------------------------------------------------------------------------
// k_attn2 (R5): 256 blocks (one per batch). Sum the two c-half partials,
// softmax over j, then xa = att @ X -> XA.
// ---------------------------------------------------------------------------
__global__ __launch_bounds__(256) void k_attn2(
    const float* __restrict__ X, const float* __restrict__ epart,
    float* __restrict__ XA)
{
    __shared__ __align__(16) float Xs[80 * 132];   // 42.2 KB
    __shared__ float e[80 * 85];                   // 27.2 KB
    int tid = threadIdx.x;
    int b = blockIdx.x;
    const float* Xb = X + (size_t)b * NN * D1;

#pragma unroll
    for (int q = 0; q < 40; ++q) {
        int t = q * 256 + tid;
        int r = t >> 7, d = t & 127;
        Xs[r * 132 + d] = (r < NN) ? Xb[(size_t)r * D1 + d] : 0.0f;
    }
    const float* e0 = epart + (size_t)(b * 2) * 6400;
    const float* e1 = e0 + 6400;
    for (int t = tid; t < 6400; t += 256) {
        int i = t / 80, j = t - i * 80;
        e[i * 85 + j] = e0[t] + e1[t];
    }
    __syncthreads();

    // softmax over j per row (rows 0..66)
    if (tid < NN) {
        float* er = e + tid * 85;
        float mx = -1e30f;
        for (int j = 0; j < NN; ++j) mx = fmaxf(mx, er[j]);
        float sum = 0.0f;
        for (int j = 0; j < NN; ++j) { float p = expf(er[j] - mx); er[j] = p; sum += p; }
        float inv = 1.0f / sum;
        for (int j = 0; j < NN; ++j) er[j] *= inv;
    }
    __syncthreads();

    // xa[i][d] = sum_j att[i][j] * X[j][d]
    int ti = tid >> 4, tj = tid & 15;
    int d0 = tj * 8;
    float o[5][8];
#pragma unroll
    for (int a = 0; a < 5; ++a)
#pragma unroll
        for (int dd = 0; dd < 8; ++dd) o[a][dd] = 0.0f;
    for (int j = 0; j < NN; ++j) {
        float4 x0 = *(const float4*)(Xs + j * 132 + d0);
        float4 x1 = *(const float4*)(Xs + j * 132 + d0 + 4);
        float av[5];
#pragma unroll
        for (int a = 0; a < 5; ++a) av[a] = e[(ti + 16 * a) * 85 + j];
#pragma unroll
        for (int a = 0; a < 5; ++a) {
            o[a][0] += av[a] * x0.x; o[a][1] += av[a] * x0.y;
            o[a][2] += av[a] * x0.z; o[a][3] += av[a] * x0.w;
            o[a][4] += av[a] * x1.x; o[a][5] += av[a] * x1.y;
            o[a][6] += av[a] * x1.z; o[a][7] += av[a] * x1.w;
        }
    }
#pragma unroll
    for (int a = 0; a < 5; ++a) {
        int i = ti + 16 * a;
        if (i < NN) {
            float* dst = XA + (size_t)(b * NN + i) * D1 + d0;
            float4 s0, s1;
            s0.x = o[a][0]; s0.y = o[a][1]; s0.z = o[a][2]; s0.w = o[a][3];
            s1.x = o[a][4]; s1.y = o[a][5]; s1.z = o[a][6]; s1.w = o[a][7];
            *(float4*)(dst) = s0;
            *(float4*)(dst + 4) = s1;
        }
    }
}

// ---------------------------------------------------------------------------
// k_gemm2: h = selu(bn2( xa@Wpa + bpa + x@Wpn + bpn )). (unchanged)
// ---------------------------------------------------------------------------
__global__ __launch_bounds__(256) void k_gemm2(
    const float* __restrict__ XAg, const float* __restrict__ Xg,
    const float* __restrict__ Wpa, const float* __restrict__ Wpn,
    const float* __restrict__ bpa, const float* __restrict__ bpn,
    const float* __restrict__ g2, const float* __restrict__ b2,
    const float* __restrict__ m2, const float* __restrict__ r2,
    float* __restrict__ h)
{
    __shared__ __align__(16) float As[64 * 260];
    __shared__ __align__(16) float Ws[256 * 68];
    int tid = threadIdx.x;
    int row0 = blockIdx.x * 64;
#pragma unroll
    for (int q = 0; q < 16; ++q) {
        int e4 = q * 256 + tid;
        int r = e4 >> 6, k4 = (e4 & 63) * 4;
        float4 v;
        if (k4 < 128) v = *(const float4*)(XAg + (size_t)(row0 + r) * D1 + k4);
        else          v = *(const float4*)(Xg + (size_t)(row0 + r) * D1 + (k4 - 128));
        *(float4*)(As + r * 260 + k4) = v;
    }
#pragma unroll
    for (int q = 0; q < 16; ++q) {
        int e4 = q * 256 + tid;
        int k = e4 >> 4, c4 = (e4 & 15) * 4;
        float4 v;
        if (k < 128) v = *(const float4*)(Wpa + k * D2 + c4);
        else         v = *(const float4*)(Wpn + (k - 128) * D2 + c4);
        *(float4*)(Ws + k * 68 + c4) = v;
    }
    __syncthreads();
    int rl = tid >> 2, cq = (tid & 3) * 16;
    float acc[16];
#pragma unroll
    for (int m = 0; m < 16; ++m) acc[m] = 0.0f;
    for (int k = 0; k < 256; ++k) {
        float a = As[rl * 260 + k];
        float4 w0 = *(const float4*)(Ws + k * 68 + cq);
        float4 w1 = *(const float4*)(Ws + k * 68 + cq + 4);
        float4 w2 = *(const float4*)(Ws + k * 68 + cq + 8);
        float4 w3 = *(const float4*)(Ws + k * 68 + cq + 12);
        acc[0] += a * w0.x;  acc[1] += a * w0.y;  acc[2] += a * w0.z;  acc[3] += a * w0.w;
        acc[4] += a * w1.x;  acc[5] += a * w1.y;  acc[6] += a * w1.z;  acc[7] += a * w1.w;
        acc[8] += a * w2.x;  acc[9] += a * w2.y;  acc[10] += a * w2.z; acc[11] += a * w2.w;
        acc[12] += a * w3.x; acc[13] += a * w3.y; acc[14] += a * w3.z; acc[15] += a * w3.w;
    }
#pragma unroll
    for (int m = 0; m < 16; ++m) {
        int c = cq + m;
        float t = acc[m] + bpa[c] + bpn[c];
        t = (t - m2[c]) * r2[c] * g2[c] + b2[c];
        h[(size_t)(row0 + rl) * D2 + c] = selu_f(t);
    }
}

// ---------------------------------------------------------------------------
// k_head: one wave per batch. scores -> sigmoid -> rank-by-count top-53
// (desc, ties by index = jax.lax.top_k) -> proj -> W_node -> out (256x2 fp32)
// ---------------------------------------------------------------------------
__global__ __launch_bounds__(64) void k_head(
    const float* __restrict__ h, const float* __restrict__ Wpool,
    const float* __restrict__ bpool, const float* __restrict__ Wproj,
    const float* __restrict__ bproj, const float* __restrict__ Wnode,
    const float* __restrict__ bnode, float* __restrict__ out)
{
    __shared__ float sc[NN], pv[NN], sel[NP];
    int lane = threadIdx.x, b = blockIdx.x;
    for (int j = lane; j < NN; j += 64) {
        const float* hr = h + (size_t)(b * NN + j) * D2;
        float z = 0.0f;
        for (int c = 0; c < D2; ++c) z += hr[c] * Wpool[c];
        z += bpool[0];
        float s = 1.0f / (1.0f + expf(-z));
        float q = 0.0f;
        for (int c = 0; c < D2; ++c) q += (hr[c] * s) * Wproj[c];
        q += bproj[0];
        sc[j] = s; pv[j] = q;
    }
    __syncthreads();
    for (int j = lane; j < NN; j += 64) {
        float sj = sc[j]; int rank = 0;
        for (int k = 0; k < NN; ++k) {
            float sk = sc[k];
            rank += (sk > sj) || (sk == sj && k < j);
        }
        if (rank < NP) sel[rank] = pv[j];
    }
    __syncthreads();
    if (lane < 2) {
        float o = 0.0f;
        for (int r = 0; r < NP; ++r) o += sel[r] * Wnode[r * 2 + lane];
        out[b * 2 + lane] = o + bnode[lane];
    }
}

// ---------------------------------------------------------------------------
extern "C" void kernel_launch(void* const* d_in, const int* in_sizes, int n_in,
                              void* d_out, int out_size, void* d_ws, size_t ws_size,
                              hipStream_t stream)
{
    const float* feat  = (const float*)d_in[0];
    const float* Wll   = (const float*)d_in[1];
    const float* bll   = (const float*)d_in[2];
    const float* g1    = (const float*)d_in[3];
    const float* b1    = (const float*)d_in[4];
    const float* m1    = (const float*)d_in[5];
    const float* v1    = (const float*)d_in[6];
    const float* Wap   = (const float*)d_in[7];
    const float* bap   = (const float*)d_in[8];
    const float* attw  = (const float*)d_in[9];
    const float* Wpa   = (const float*)d_in[10];
    const float* bpa   = (const float*)d_in[11];
    const float* Wpn   = (const float*)d_in[12];
    const float* bpn   = (const float*)d_in[13];
    const float* g2    = (const float*)d_in[14];
    const float* b2    = (const float*)d_in[15];
    const float* m2    = (const float*)d_in[16];
    const float* v2    = (const float*)d_in[17];
    const float* Wpool = (const float*)d_in[18];
    const float* bpool = (const float*)d_in[19];
    const float* Wproj = (const float*)d_in[20];
    const float* bproj = (const float*)d_in[21];
    const float* Wnode = (const float*)d_in[22];
    const float* bnode = (const float*)d_in[23];
    float* out = (float*)d_out;

    char* w = (char*)d_ws;
    float* y    = (float*)w; w += (size_t)ROWS1 * D1 * 4;   // 26.3 MB; dead after
    float* X    = (float*)w; w += (size_t)ROWS2 * D1 * 4;   //   k_pool -> reused
    float* XA   = (float*)w; w += (size_t)ROWS2 * D1 * 4;   //   as epart below
    float* hbuf = (float*)w; w += (size_t)ROWS2 * D2 * 4;
    float* WllT = (float*)w; w += (size_t)128 * 1024 * 4;
    float* WapT = (float*)w; w += (size_t)64 * 128 * 4;
    float* r1   = (float*)w; w += 128 * 4;
    float* r2   = (float*)w; w += 64 * 4;
    float* epart = y;   // 512*6400*4 = 13.1 MB <= 26.3 MB (y dead after k_pool)

    hipLaunchKernelGGL(k_pre,   dim3(545),  dim3(256), 0, stream,
                       Wll, Wap, v1, v2, WllT, WapT, r1, r2);
    hipLaunchKernelGGL(k_gemm1, dim3(402),  dim3(256), 0, stream, feat, WllT, y);
    hipLaunchKernelGGL(k_pool,  dim3(8576), dim3(256), 0, stream,
                       y, bll, g1, b1, m1, r1, X);
    hipLaunchKernelGGL(k_attn1, dim3(512),  dim3(256), 0, stream,
                       X, WapT, bap, attw, epart);
    hipLaunchKernelGGL(k_attn2, dim3(256),  dim3(256), 0, stream,
                       X, epart, XA);
    hipLaunchKernelGGL(k_gemm2, dim3(268),  dim3(256), 0, stream,
                       XA, X, Wpa, Wpn, bpa, bpn, g2, b2, m2, r2, hbuf);
    hipLaunchKernelGGL(k_head,  dim3(256),  dim3(64),  0, stream,
                       hbuf, Wpool, bpool, Wproj, bproj, Wnode, bnode, out);
}